// Round 1
// baseline (119.018 us; speedup 1.0000x reference)
//
#include <hip/hip_runtime.h>

#define BATCH 16384
#define DIM   512
#define NCLS  2048

typedef _Float16 half8 __attribute__((ext_vector_type(8)));
typedef float    floatx4 __attribute__((ext_vector_type(4)));

#define GLB(p) ((const __attribute__((address_space(1))) void*)(p))
#define LDSP(p) ((__attribute__((address_space(3))) void*)(p))

// ---------------- fp32 -> fp16 convert (8 elems/thread) ----------------
__global__ __launch_bounds__(256) void cvt_kernel(const float* __restrict__ src,
                                                  _Float16* __restrict__ dst) {
    size_t i = ((size_t)blockIdx.x * 256 + threadIdx.x) * 8;
    float4 a = *reinterpret_cast<const float4*>(src + i);
    float4 b = *reinterpret_cast<const float4*>(src + i + 4);
    half8 h;
    h[0] = (_Float16)a.x; h[1] = (_Float16)a.y; h[2] = (_Float16)a.z; h[3] = (_Float16)a.w;
    h[4] = (_Float16)b.x; h[5] = (_Float16)b.y; h[6] = (_Float16)b.z; h[7] = (_Float16)b.w;
    *reinterpret_cast<half8*>(dst + i) = h;
}

// ---------------- 0.5 * ||c_k||^2, one wave per class ----------------
__global__ __launch_bounds__(64) void csq_kernel(const float* __restrict__ c,
                                                 float* __restrict__ hcsq) {
    int k = blockIdx.x, t = threadIdx.x;
    const float4* p = reinterpret_cast<const float4*>(c + (size_t)k * DIM);
    float s = 0.f;
    #pragma unroll
    for (int j = 0; j < 2; ++j) {
        float4 v = p[t + j * 64];
        s += v.x * v.x + v.y * v.y + v.z * v.z + v.w * v.w;
    }
    #pragma unroll
    for (int o = 32; o; o >>= 1) s += __shfl_xor(s, o);
    if (t == 0) hcsq[k] = 0.5f * s;
}

// ---------------- cross = x @ centers^T  (fp16 MFMA, m97 structure) ----------------
// 128x128 tile, BK=32, 4 waves (2x2), each wave 64x64 = 4x4 fragments of 16x16x32.
__global__ __launch_bounds__(256) void gemm_kernel(const _Float16* __restrict__ A,  // [BATCH][DIM]
                                                   const _Float16* __restrict__ B,  // [NCLS][DIM]
                                                   float* __restrict__ C) {         // [BATCH][NCLS]
    __shared__ __align__(16) _Float16 As[128 * 32];
    __shared__ __align__(16) _Float16 Bs[128 * 32];

    const int bid  = blockIdx.x;
    const int rowB = (bid >> 4) << 7;   // 128 row-blocks; consecutive bids share A panel
    const int colB = (bid & 15) << 7;   // 16 col-blocks
    const int tid  = threadIdx.x;
    const int lane = tid & 63;
    const int wave = tid >> 6;
    const int wr   = wave >> 1, wc = wave & 1;

    // staging: wave stages 32 rows of A-tile and 32 rows of B-tile (2 x global_load_lds each)
    const _Float16* agp = A + (size_t)(rowB + wave * 32 + (lane >> 2)) * DIM + (lane & 3) * 8;
    const _Float16* bgp = B + (size_t)(colB + wave * 32 + (lane >> 2)) * DIM + (lane & 3) * 8;
    _Float16* alp = &As[(wave * 32) * 32];
    _Float16* blp = &Bs[(wave * 32) * 32];

    // fragment read coords
    const int fko  = (lane >> 4) * 8;           // k-offset within BK=32 (halves)
    const int arow = wr * 64 + (lane & 15);
    const int brow = wc * 64 + (lane & 15);

    floatx4 acc[4][4] = {};

    for (int kk = 0; kk < DIM / 32; ++kk) {
        __builtin_amdgcn_global_load_lds(GLB(agp),            LDSP(alp),           16, 0, 0);
        __builtin_amdgcn_global_load_lds(GLB(agp + 16 * DIM), LDSP(alp + 16 * 32), 16, 0, 0);
        __builtin_amdgcn_global_load_lds(GLB(bgp),            LDSP(blp),           16, 0, 0);
        __builtin_amdgcn_global_load_lds(GLB(bgp + 16 * DIM), LDSP(blp + 16 * 32), 16, 0, 0);
        agp += 32;
        bgp += 32;
        __syncthreads();   // drains vmcnt -> staged data visible

        half8 af[4], bf[4];
        #pragma unroll
        for (int m = 0; m < 4; ++m)
            af[m] = *reinterpret_cast<const half8*>(&As[(arow + m * 16) * 32 + fko]);
        #pragma unroll
        for (int n = 0; n < 4; ++n)
            bf[n] = *reinterpret_cast<const half8*>(&Bs[(brow + n * 16) * 32 + fko]);

        #pragma unroll
        for (int m = 0; m < 4; ++m)
            #pragma unroll
            for (int n = 0; n < 4; ++n)
                acc[m][n] = __builtin_amdgcn_mfma_f32_16x16x32_f16(af[m], bf[n], acc[m][n], 0, 0, 0);

        __syncthreads();   // all reads done before next stage overwrites
    }

    // C/D layout: col = lane&15, row = (lane>>4)*4 + j
    const int crow = rowB + wr * 64 + ((lane >> 4) << 2);
    const int ccol = colB + wc * 64 + (lane & 15);
    #pragma unroll
    for (int m = 0; m < 4; ++m)
        #pragma unroll
        for (int n = 0; n < 4; ++n)
            #pragma unroll
            for (int j = 0; j < 4; ++j)
                C[(size_t)(crow + m * 16 + j) * NCLS + ccol + n * 16] = acc[m][n][j];
}

// ---------------- in-place row softmax of (cross - 0.5*csq) ----------------
__global__ __launch_bounds__(256) void softmax_kernel(float* __restrict__ O,
                                                      const float* __restrict__ hcsq) {
    const int row  = blockIdx.x;
    const int tid  = threadIdx.x;
    const int lane = tid & 63, wave = tid >> 6;

    float4* Orow = reinterpret_cast<float4*>(O + (size_t)row * NCLS);
    const float4* Q = reinterpret_cast<const float4*>(hcsq);

    float4 v0 = Orow[tid];
    float4 v1 = Orow[tid + 256];
    float4 q0 = Q[tid];
    float4 q1 = Q[tid + 256];
    v0.x -= q0.x; v0.y -= q0.y; v0.z -= q0.z; v0.w -= q0.w;
    v1.x -= q1.x; v1.y -= q1.y; v1.z -= q1.z; v1.w -= q1.w;

    // row max
    float m = fmaxf(fmaxf(fmaxf(v0.x, v0.y), fmaxf(v0.z, v0.w)),
                    fmaxf(fmaxf(v1.x, v1.y), fmaxf(v1.z, v1.w)));
    #pragma unroll
    for (int o = 32; o; o >>= 1) m = fmaxf(m, __shfl_xor(m, o));
    __shared__ float redm[4];
    __shared__ float reds[4];
    if (lane == 0) redm[wave] = m;
    __syncthreads();
    m = fmaxf(fmaxf(redm[0], redm[1]), fmaxf(redm[2], redm[3]));

    // exp + sum
    v0.x = __expf(v0.x - m); v0.y = __expf(v0.y - m); v0.z = __expf(v0.z - m); v0.w = __expf(v0.w - m);
    v1.x = __expf(v1.x - m); v1.y = __expf(v1.y - m); v1.z = __expf(v1.z - m); v1.w = __expf(v1.w - m);
    float s = v0.x + v0.y + v0.z + v0.w + v1.x + v1.y + v1.z + v1.w;
    #pragma unroll
    for (int o = 32; o; o >>= 1) s += __shfl_xor(s, o);
    if (lane == 0) reds[wave] = s;
    __syncthreads();
    s = reds[0] + reds[1] + reds[2] + reds[3];

    float inv = 1.0f / s;
    v0.x *= inv; v0.y *= inv; v0.z *= inv; v0.w *= inv;
    v1.x *= inv; v1.y *= inv; v1.z *= inv; v1.w *= inv;
    Orow[tid]       = v0;
    Orow[tid + 256] = v1;
}

extern "C" void kernel_launch(void* const* d_in, const int* in_sizes, int n_in,
                              void* d_out, int out_size, void* d_ws, size_t ws_size,
                              hipStream_t stream) {
    const float* x       = (const float*)d_in[0];
    const float* centers = (const float*)d_in[1];
    float* out = (float*)d_out;

    // ws layout: x_fp16 [BATCH*DIM] | c_fp16 [NCLS*DIM] | 0.5*csq [NCLS]  (~18.9 MB)
    _Float16* xh = (_Float16*)d_ws;
    _Float16* ch = xh + (size_t)BATCH * DIM;
    float* hcsq  = (float*)(ch + (size_t)NCLS * DIM);

    hipLaunchKernelGGL(cvt_kernel, dim3(BATCH * DIM / (8 * 256)), dim3(256), 0, stream, x, xh);
    hipLaunchKernelGGL(cvt_kernel, dim3(NCLS * DIM / (8 * 256)), dim3(256), 0, stream, centers, ch);
    hipLaunchKernelGGL(csq_kernel, dim3(NCLS), dim3(64), 0, stream, centers, hcsq);
    hipLaunchKernelGGL(gemm_kernel, dim3((BATCH / 128) * (NCLS / 128)), dim3(256), 0, stream,
                       xh, ch, out);
    hipLaunchKernelGGL(softmax_kernel, dim3(BATCH), dim3(256), 0, stream, out, hcsq);
}